// Round 12
// baseline (171.997 us; speedup 1.0000x reference)
//
#include <hip/hip_runtime.h>
#include <hip/hip_bf16.h>
#include <cstddef>
#include <math.h>

// Problem constants (from reference)
#define N_NODES 16384   // B*A
#define DIN 64
#define HID 128
#define SCALE_F 0.17677669529663687f  // 1/sqrt(32)

using bf16x8 = __attribute__((ext_vector_type(8))) short;   // 8 bf16 = 4 VGPRs
using f32x4  = __attribute__((ext_vector_type(4))) float;   // MFMA acc

__device__ __forceinline__ ushort f2b(float x) {
  __hip_bfloat16 h = __float2bfloat16(x);
  return *(ushort*)&h;
}
__device__ __forceinline__ float b2f(ushort u) {
  __hip_bfloat16 h = *(__hip_bfloat16*)&u;
  return __bfloat162float(h);
}
// fp32 -> 2-way split (hi+lo), err ~2^-17 |x|
__device__ __forceinline__ void split1(float x, ushort& h, ushort& l) {
  h = f2b(x);
  l = f2b(x - b2f(h));
}
// fp32 -> 3-way split (a+b+c), err ~2^-27 |x|  (F/M path, proven)
__device__ __forceinline__ void split3(float x, ushort& a, ushort& b, ushort& c) {
  a = f2b(x);
  float r1 = x - b2f(a);
  b = f2b(r1);
  c = f2b(r1 - b2f(b));
}

#define MFMA(d, A, B) d = __builtin_amdgcn_mfma_f32_16x16x32_bf16(A, B, d, 0, 0, 0)

// ---------------- merged prep: G, M0, M1, W1/W2 splits, zero(out) ----------------
// block ranges: [0] G | [1,129) M0 | [129,385) M1 | [385,769) splitW | [769,833) zero

__global__ __launch_bounds__(256) void prep_all_kernel(
    const float* __restrict__ Wq0, const float* __restrict__ Wk0,
    const float* __restrict__ Wq1, const float* __restrict__ Wk1,
    float* __restrict__ G,
    const float* __restrict__ Wv0, const float* __restrict__ Wo0,
    ushort* __restrict__ M0a, ushort* __restrict__ M0b, ushort* __restrict__ M0c,
    const float* __restrict__ Wv1, const float* __restrict__ Wo1,
    ushort* __restrict__ M1a, ushort* __restrict__ M1b, ushort* __restrict__ M1c,
    const float* __restrict__ W1, ushort* __restrict__ W1hi, ushort* __restrict__ W1lo,
    const float* __restrict__ W2, ushort* __restrict__ W2hi, ushort* __restrict__ W2lo,
    unsigned long long* __restrict__ out64)
{
  int blk = blockIdx.x, t = threadIdx.x;
  if (blk == 0) {
    if (t >= 32) return;
    int l = t >> 4, h = (t >> 2) & 3, a = (t >> 1) & 1, b = t & 1;
    const float* Wq = l ? Wq1 : Wq0;
    const float* Wk = l ? Wk1 : Wk0;
    float acc = 0.f;
    for (int c = 0; c < 128; c++)
      acc += Wq[(h * 128 + c) * 2 + a] * Wk[(h * 128 + c) * 2 + b];
    G[t] = acc;
  } else if (blk < 385) {
    // folded M = Wv^T-contract-Wo, triple-split
    int D, idx;
    const float *Wv, *Wo;
    ushort *Ma, *Mb, *Mc;
    if (blk < 129) { D = DIN; idx = (blk - 1) * 256 + t; Wv = Wv0; Wo = Wo0; Ma = M0a; Mb = M0b; Mc = M0c; }
    else           { D = HID; idx = (blk - 129) * 256 + t; Wv = Wv1; Wo = Wo1; Ma = M1a; Mb = M1b; Mc = M1c; }
    int K4 = 4 * D;
    int o = idx / K4, hd = idx - o * K4;
    int h = hd / D, d = hd - h * D;
    const float* wv = Wv + (size_t)(h * 128) * D + d;
    const float* wo = Wo + (size_t)o * 512 + h * 128;
    float acc = 0.f;
    for (int c = 0; c < 128; c++)
      acc += wv[(size_t)c * D] * wo[c];
    split3(acc, Ma[idx], Mb[idx], Mc[idx]);
  } else if (blk < 769) {
    int i = (blk - 385) * 256 + t;
    if (i < 256 * 128) split1(W1[i], W1hi[i], W1lo[i]);
    int j = i - 256 * 128;
    if (j >= 0 && j < 256 * 256) split1(W2[j], W2hi[j], W2lo[j]);
  } else {
    int i = (blk - 769) * 256 + t;
    if (i < N_NODES) out64[i] = 0ull;   // zero output (atomic W3 accumulation)
  }
}

// ---------------- fully fused: mask build + 2-layer GAT + 3-layer MLP ----------------
// 512 threads / block, one block per 64-node graph block (grid = 256 = 1/CU).
// GAT core: round-10 numerics (split3 F/M 6-term, split2 A/Y exact 4-term,
// self-shift softmax) restructured to HEAD PAIRS: outer hp loop (unroll 1),
// F fragments loaded once per kf and shared by both heads (halves F LDS
// reads), y[2][4] = 8 independent MFMA chains (2x ILP at 2 waves/SIMD).
// hi is fully unrolled everywhere -> all register indices compile-time
// (round-9 dynamic-VGPR-index trap avoided).

#define PF 136   // F plane pitch (ushort)

template <int KD>
__device__ __forceinline__ void gat_layer(
    int wave, int lm, int lq,
    const ushort* sFa, const ushort* sFb, const ushort* sFc,
    const float* psx, const float* psy,
    const float* pdx, const float* pdy,
    const unsigned long long* m64,
    const float* __restrict__ G,
    const ushort* __restrict__ Ma, const ushort* __restrict__ Mb,
    const ushort* __restrict__ Mc,
    f32x4 hacc[4])
{
  const int K4 = 4 * KD;
  const int o = 16 * wave + lm;
#pragma unroll
  for (int i = 0; i < 4; i++) hacc[i] = (f32x4){0.f, 0.f, 0.f, 0.f};

#pragma unroll 1
  for (int hp = 0; hp < 2; hp++) {
    // ---- Y-GEMM for head pair: y[hi][mt], F frags shared across heads ----
    f32x4 y[2][4];
#pragma unroll
    for (int hi = 0; hi < 2; hi++)
#pragma unroll
      for (int i = 0; i < 4; i++) y[hi][i] = (f32x4){0.f, 0.f, 0.f, 0.f};
#pragma unroll 1
    for (int kf = 0; kf < KD / 32; kf++) {
      bf16x8 fa[4], fb[4], fc[4];
#pragma unroll
      for (int mt = 0; mt < 4; mt++) {
        int fo = (mt * 16 + lm) * PF + kf * 32 + lq * 8;
        fa[mt] = *(const bf16x8*)&sFa[fo];
        fb[mt] = *(const bf16x8*)&sFb[fo];
        fc[mt] = *(const bf16x8*)&sFc[fo];
      }
#pragma unroll
      for (int hi = 0; hi < 2; hi++) {
        size_t boff = (size_t)o * K4 + (hp * 2 + hi) * KD + kf * 32 + lq * 8;
        bf16x8 ma = *(const bf16x8*)&Ma[boff];
        bf16x8 mb = *(const bf16x8*)&Mb[boff];
        bf16x8 mc = *(const bf16x8*)&Mc[boff];
#pragma unroll
        for (int mt = 0; mt < 4; mt++) MFMA(y[hi][mt], fa[mt], ma);
#pragma unroll
        for (int mt = 0; mt < 4; mt++) MFMA(y[hi][mt], fa[mt], mb);
#pragma unroll
        for (int mt = 0; mt < 4; mt++) MFMA(y[hi][mt], fb[mt], ma);
#pragma unroll
        for (int mt = 0; mt < 4; mt++) MFMA(y[hi][mt], fa[mt], mc);
#pragma unroll
        for (int mt = 0; mt < 4; mt++) MFMA(y[hi][mt], fc[mt], ma);
#pragma unroll
        for (int mt = 0; mt < 4; mt++) MFMA(y[hi][mt], fb[mt], mb);
      }
    }
    // ---- per-head epilogue (hi unrolled -> static indices) ----
#pragma unroll
    for (int hi = 0; hi < 2; hi++) {
      int h = hp * 2 + hi;
      // redistribute y (C-layout) -> B-frags via shuffles, split2
      bf16x8 Ya[2], Yb[2];
#pragma unroll
      for (int kb = 0; kb < 2; kb++) {
#pragma unroll
        for (int j = 0; j < 8; j++) {
          int sl = ((2 * lq + (j >> 2)) & 3) * 16 + lm;
          float v0 = __shfl(y[hi][2 * kb][j & 3], sl);
          float v1 = __shfl(y[hi][2 * kb + 1][j & 3], sl);
          float v = (lq & 2) ? v1 : v0;
          ushort ua, ub;
          split1(v, ua, ub);
          Ya[kb][j] = (short)ua; Yb[kb][j] = (short)ub;
        }
      }
      // A@Y per dst tile
      float g0 = G[h * 4], g1 = G[h * 4 + 1], g2 = G[h * 4 + 2], g3 = G[h * 4 + 3];
#pragma unroll
      for (int mtd = 0; mtd < 4; mtd++) {
        float a0 = (g0 * pdx[mtd] + g2 * pdy[mtd]) * SCALE_F;
        float a1 = (g1 * pdx[mtd] + g3 * pdy[mtd]) * SCALE_F;
        float sshift = a0 * pdx[mtd] + a1 * pdy[mtd];  // self-loop score (in mask)
        unsigned mb0 = (unsigned)((m64[mtd] >> (8 * lq)) & 0xFF);
        unsigned mb1 = (unsigned)((m64[mtd] >> (32 + 8 * lq)) & 0xFF);
        float e[16];
        float sum = 0.f;
#pragma unroll
        for (int j = 0; j < 8; j++) {
          e[j]     = ((mb0 >> j) & 1) ? __expf(a0 * psx[j] + a1 * psy[j] - sshift) : 0.f;
          e[8 + j] = ((mb1 >> j) & 1) ? __expf(a0 * psx[8 + j] + a1 * psy[8 + j] - sshift) : 0.f;
          sum += e[j] + e[8 + j];
        }
        sum += __shfl_xor(sum, 16);
        sum += __shfl_xor(sum, 32);
        float inv = 1.f / sum;
        bf16x8 Aa[2], Ab[2];
#pragma unroll
        for (int j = 0; j < 8; j++) {
          ushort ua, ub;
          split1(e[j] * inv, ua, ub);
          Aa[0][j] = (short)ua; Ab[0][j] = (short)ub;
          split1(e[8 + j] * inv, ua, ub);
          Aa[1][j] = (short)ua; Ab[1][j] = (short)ub;
        }
#pragma unroll
        for (int kb = 0; kb < 2; kb++) {
          MFMA(hacc[mtd], Aa[kb], Ya[kb]);
          MFMA(hacc[mtd], Aa[kb], Yb[kb]);
          MFMA(hacc[mtd], Ab[kb], Ya[kb]);
          MFMA(hacc[mtd], Ab[kb], Yb[kb]);
        }
      }
    }
  }
}

__global__ __attribute__((amdgpu_flat_work_group_size(512, 512), amdgpu_waves_per_eu(2)))
void fused_gat_kernel(
    const float* __restrict__ x, const float* __restrict__ pos,
    const int* __restrict__ srcp, const int* __restrict__ dstp,
    const float* __restrict__ G,
    const ushort* __restrict__ M0a, const ushort* __restrict__ M0b, const ushort* __restrict__ M0c,
    const ushort* __restrict__ M1a, const ushort* __restrict__ M1b, const ushort* __restrict__ M1c,
    const float* __restrict__ bo0, const float* __restrict__ bo1,
    const ushort* __restrict__ W1hi, const ushort* __restrict__ W1lo, const float* __restrict__ b1,
    const ushort* __restrict__ W2hi, const ushort* __restrict__ W2lo, const float* __restrict__ b2,
    const float* __restrict__ W3, const float* __restrict__ b3,
    float* __restrict__ outp)
{
  // 64KB union. GAT: sF planes [0,26112) + px/py [26112,26368) + smask [26368,26624).
  // MLP: h2 split2 in sFa/sFb [0,17408) (dies at B7), then out1 planes [0,32768).
  __shared__ __align__(16) ushort uBig[32768];
  ushort* sFa = uBig;
  ushort* sFb = uBig + 8704;
  ushort* sFc = uBig + 17408;
  float* pxs = (float*)(uBig + 26112);
  float* pys = (float*)(uBig + 26240);
  unsigned long long* smask = (unsigned long long*)(uBig + 26368);
  ushort* pA = uBig;
  ushort* pB = uBig + 16384;

  int b = blockIdx.x, t = threadIdx.x;
  int wave = t >> 6, lane = t & 63, lm = lane & 15, lq = lane >> 4;

  if (t < 64) {
    pxs[t] = pos[(b * 64 + t) * 2];
    pys[t] = pos[(b * 64 + t) * 2 + 1];
    smask[t] = 1ull << t;   // self-loop bit
  }
  // stage X (64x64 fp32) -> triple-split planes
  {
    const float4* gx = (const float4*)(x + (size_t)b * 64 * DIN);
#pragma unroll
    for (int i = 0; i < 2; i++) {
      int idx = t + i * 512;
      float4 v = gx[idx];
      int r = idx >> 4, c = (idx & 15) * 4;
      ushort4 ua, ub, uc;
      split3(v.x, ua.x, ub.x, uc.x); split3(v.y, ua.y, ub.y, uc.y);
      split3(v.z, ua.z, ub.z, uc.z); split3(v.w, ua.w, ub.w, uc.w);
      *(ushort4*)&sFa[r * PF + c] = ua;
      *(ushort4*)&sFb[r * PF + c] = ub;
      *(ushort4*)&sFc[r * PF + c] = uc;
    }
  }
  __syncthreads();   // B1: smask init + X visible
  // adjacency from this block's own 448 kNN edge rows (reference (B,A,K) C-order)
  if (t < 448) {
    int s = srcp[b * 448 + t];
    int d = dstp[b * 448 + t];
    atomicOr(&smask[d & 63], 1ull << (s & 63));
  }
  __syncthreads();   // B2
  unsigned long long m64[4];
#pragma unroll
  for (int mtd = 0; mtd < 4; mtd++) m64[mtd] = smask[mtd * 16 + lm];

  float psx[16], psy[16], pdx[4], pdy[4];
#pragma unroll
  for (int j = 0; j < 8; j++) {
    psx[j] = pxs[8 * lq + j];          psy[j] = pys[8 * lq + j];
    psx[8 + j] = pxs[32 + 8 * lq + j]; psy[8 + j] = pys[32 + 8 * lq + j];
  }
#pragma unroll
  for (int mtd = 0; mtd < 4; mtd++) {
    pdx[mtd] = pxs[mtd * 16 + lm];
    pdy[mtd] = pys[mtd * 16 + lm];
  }

  f32x4 hacc[4];
  gat_layer<DIN>(wave, lm, lq, sFa, sFb, sFc, psx, psy, pdx, pdy, m64,
                 G, M0a, M0b, M0c, hacc);
  __syncthreads();   // B3: layer-0 F reads done
  int o = 16 * wave + lm;
  {
    float bv = bo0[o];
#pragma unroll
    for (int mtd = 0; mtd < 4; mtd++)
#pragma unroll
      for (int r = 0; r < 4; r++) {
        int dst = mtd * 16 + lq * 4 + r;
        ushort ua, ub, uc;
        split3(tanhf(hacc[mtd][r] + bv), ua, ub, uc);
        sFa[dst * PF + o] = ua;
        sFb[dst * PF + o] = ub;
        sFc[dst * PF + o] = uc;
      }
  }
  __syncthreads();   // B4
  gat_layer<HID>(wave, lm, lq, sFa, sFb, sFc, psx, psy, pdx, pdy, m64,
                 G + 16, M1a, M1b, M1c, hacc);
  // h2 in regs
  float h2v[4][4];
  {
    float bv = bo1[o];
#pragma unroll
    for (int mtd = 0; mtd < 4; mtd++)
#pragma unroll
      for (int r = 0; r < 4; r++)
        h2v[mtd][r] = tanhf(hacc[mtd][r] + bv);
  }
  __syncthreads();   // B5: layer-1 sF reads done
  // store h2 split2 into sFa/sFb
#pragma unroll
  for (int mtd = 0; mtd < 4; mtd++)
#pragma unroll
    for (int r = 0; r < 4; r++) {
      int dst = mtd * 16 + lq * 4 + r;
      ushort hh, ll;
      split1(h2v[mtd][r], hh, ll);
      sFa[dst * PF + o] = hh;
      sFb[dst * PF + o] = ll;
    }
  __syncthreads();   // B6
  // ---- W1: out1 = relu(h2 @ W1^T + b1); wave cols [32w, 32w+32) ----
  f32x4 y1[2][4];
#pragma unroll
  for (int ti = 0; ti < 2; ti++)
#pragma unroll
    for (int mtd = 0; mtd < 4; mtd++) y1[ti][mtd] = (f32x4){0.f, 0.f, 0.f, 0.f};
#pragma unroll 1
  for (int kf = 0; kf < 4; kf++) {
    int ko = kf * 32 + lq * 8;
    bf16x8 bh0 = *(const bf16x8*)&W1hi[(size_t)(32 * wave + lm) * 128 + ko];
    bf16x8 bl0 = *(const bf16x8*)&W1lo[(size_t)(32 * wave + lm) * 128 + ko];
    bf16x8 bh1 = *(const bf16x8*)&W1hi[(size_t)(32 * wave + 16 + lm) * 128 + ko];
    bf16x8 bl1 = *(const bf16x8*)&W1lo[(size_t)(32 * wave + 16 + lm) * 128 + ko];
#pragma unroll
    for (int mtd = 0; mtd < 4; mtd++) {
      bf16x8 ah = *(const bf16x8*)&sFa[(mtd * 16 + lm) * PF + ko];
      bf16x8 al = *(const bf16x8*)&sFb[(mtd * 16 + lm) * PF + ko];
      MFMA(y1[0][mtd], ah, bh0);
      MFMA(y1[0][mtd], ah, bl0);
      MFMA(y1[0][mtd], al, bh0);
      MFMA(y1[1][mtd], ah, bh1);
      MFMA(y1[1][mtd], ah, bl1);
      MFMA(y1[1][mtd], al, bh1);
    }
  }
  __syncthreads();   // B7: all W1 h2-reads done; pA/pB may overwrite
  // store out1 split2, XOR-swizzled: elem (row,k) at row*256 + (k ^ ((row&15)<<3))
#pragma unroll
  for (int ti = 0; ti < 2; ti++) {
    int col = 32 * wave + ti * 16 + lm;
    float bv = b1[col];
#pragma unroll
    for (int mtd = 0; mtd < 4; mtd++)
#pragma unroll
      for (int r = 0; r < 4; r++) {
        int row = mtd * 16 + lq * 4 + r;
        float v = fmaxf(y1[ti][mtd][r] + bv, 0.f);
        ushort hh, ll;
        split1(v, hh, ll);
        int cc = col ^ ((row & 15) << 3);
        pA[row * 256 + cc] = hh;
        pB[row * 256 + cc] = ll;
      }
  }
  __syncthreads();   // B8
  // ---- W2 + fused W3 ----
  f32x4 y2[2][4];
#pragma unroll
  for (int ti = 0; ti < 2; ti++)
#pragma unroll
    for (int mtd = 0; mtd < 4; mtd++) y2[ti][mtd] = (f32x4){0.f, 0.f, 0.f, 0.f};
#pragma unroll 1
  for (int kf = 0; kf < 8; kf++) {
    int ko = kf * 32 + lq * 8;
    bf16x8 bh0 = *(const bf16x8*)&W2hi[(size_t)(32 * wave + lm) * 256 + ko];
    bf16x8 bl0 = *(const bf16x8*)&W2lo[(size_t)(32 * wave + lm) * 256 + ko];
    bf16x8 bh1 = *(const bf16x8*)&W2hi[(size_t)(32 * wave + 16 + lm) * 256 + ko];
    bf16x8 bl1 = *(const bf16x8*)&W2lo[(size_t)(32 * wave + 16 + lm) * 256 + ko];
#pragma unroll
    for (int mtd = 0; mtd < 4; mtd++) {
      int row = mtd * 16 + lm;
      int cc = ko ^ ((row & 15) << 3);
      bf16x8 ah = *(const bf16x8*)&pA[row * 256 + cc];
      bf16x8 al = *(const bf16x8*)&pB[row * 256 + cc];
      MFMA(y2[0][mtd], ah, bh0);
      MFMA(y2[0][mtd], ah, bl0);
      MFMA(y2[0][mtd], al, bh0);
      MFMA(y2[1][mtd], ah, bh1);
      MFMA(y2[1][mtd], ah, bl1);
      MFMA(y2[1][mtd], al, bh1);
    }
  }
  // W3 epilogue: per-row dot over this wave's 32 cols, lm-reduce, atomicAdd
  {
    int c0 = 32 * wave + lm, c1 = c0 + 16;
    float w300 = W3[c0], w301 = W3[c1];
    float w310 = W3[256 + c0], w311 = W3[256 + c1];
    float b20 = b2[c0], b21 = b2[c1];
    float bb0 = (wave == 0) ? b3[0] : 0.f;
    float bb1 = (wave == 0) ? b3[1] : 0.f;
#pragma unroll
    for (int mtd = 0; mtd < 4; mtd++)
#pragma unroll
      for (int r = 0; r < 4; r++) {
        float va = fmaxf(y2[0][mtd][r] + b20, 0.f);
        float vb = fmaxf(y2[1][mtd][r] + b21, 0.f);
        float s0 = va * w300 + vb * w301;
        float s1 = va * w310 + vb * w311;
        s0 += __shfl_xor(s0, 1); s0 += __shfl_xor(s0, 2);
        s0 += __shfl_xor(s0, 4); s0 += __shfl_xor(s0, 8);
        s1 += __shfl_xor(s1, 1); s1 += __shfl_xor(s1, 2);
        s1 += __shfl_xor(s1, 4); s1 += __shfl_xor(s1, 8);
        if (lm == 0) {
          int row = b * 64 + mtd * 16 + lq * 4 + r;
          atomicAdd(&outp[row * 2 + 0], s0 + bb0);
          atomicAdd(&outp[row * 2 + 1], s1 + bb1);
        }
      }
  }
}

// ---------------- launch ----------------

extern "C" void kernel_launch(void* const* d_in, const int* in_sizes, int n_in,
                              void* d_out, int out_size, void* d_ws, size_t ws_size,
                              hipStream_t stream) {
  const float* x     = (const float*)d_in[0];
  const float* pos   = (const float*)d_in[1];
  const int*   ei    = (const int*)d_in[2];
  const float* l0_Wq = (const float*)d_in[3];
  const float* l0_Wk = (const float*)d_in[4];
  const float* l0_Wv = (const float*)d_in[5];
  const float* l0_Wo = (const float*)d_in[6];
  const float* l0_bo = (const float*)d_in[7];
  const float* l1_Wq = (const float*)d_in[8];
  const float* l1_Wk = (const float*)d_in[9];
  const float* l1_Wv = (const float*)d_in[10];
  const float* l1_Wo = (const float*)d_in[11];
  const float* l1_bo = (const float*)d_in[12];
  const float* W1    = (const float*)d_in[13];
  const float* b1    = (const float*)d_in[14];
  const float* W2    = (const float*)d_in[15];
  const float* b2    = (const float*)d_in[16];
  const float* W3    = (const float*)d_in[17];
  const float* b3    = (const float*)d_in[18];
  float* outp = (float*)d_out;

  int E = in_sizes[2] / 2;
  const int* srcp = ei;
  const int* dstp = ei + E;

  char* base = (char*)d_ws;
  size_t off = 0;
  auto alloc = [&](size_t bytes) -> void* {
    void* p = base + off;
    off = (off + bytes + 255) & ~(size_t)255;
    return p;
  };
  float*  G   = (float*)alloc(32 * sizeof(float));
  ushort* M0a = (ushort*)alloc((size_t)128 * 256 * 2);
  ushort* M0b = (ushort*)alloc((size_t)128 * 256 * 2);
  ushort* M0c = (ushort*)alloc((size_t)128 * 256 * 2);
  ushort* M1a = (ushort*)alloc((size_t)128 * 512 * 2);
  ushort* M1b = (ushort*)alloc((size_t)128 * 512 * 2);
  ushort* M1c = (ushort*)alloc((size_t)128 * 512 * 2);
  ushort* W1hi = (ushort*)alloc((size_t)256 * 128 * 2);
  ushort* W1lo = (ushort*)alloc((size_t)256 * 128 * 2);
  ushort* W2hi = (ushort*)alloc((size_t)256 * 256 * 2);
  ushort* W2lo = (ushort*)alloc((size_t)256 * 256 * 2);

  // prep: G, M folds, W splits, zero(out)
  prep_all_kernel<<<833, 256, 0, stream>>>(
      l0_Wq, l0_Wk, l1_Wq, l1_Wk, G,
      l0_Wv, l0_Wo, M0a, M0b, M0c,
      l1_Wv, l1_Wo, M1a, M1b, M1c,
      W1, W1hi, W1lo, W2, W2hi, W2lo,
      (unsigned long long*)outp);

  // fully fused network
  fused_gat_kernel<<<N_NODES / 64, 512, 0, stream>>>(
      x, pos, srcp, dstp, G, M0a, M0b, M0c, M1a, M1b, M1c, l0_bo, l1_bo,
      W1hi, W1lo, b1, W2hi, W2lo, b2, W3, b3, outp);

  (void)n_in; (void)out_size; (void)ws_size;
}

// Round 13
// 168.565 us; speedup vs baseline: 1.0204x; 1.0204x over previous
//
#include <hip/hip_runtime.h>
#include <hip/hip_bf16.h>
#include <cstddef>
#include <math.h>

// Problem constants (from reference)
#define N_NODES 16384   // B*A
#define DIN 64
#define HID 128
#define SCALE_F 0.17677669529663687f  // 1/sqrt(32)

using bf16x8 = __attribute__((ext_vector_type(8))) short;   // 8 bf16 = 4 VGPRs
using f32x4  = __attribute__((ext_vector_type(4))) float;   // MFMA acc

__device__ __forceinline__ ushort f2b(float x) {
  __hip_bfloat16 h = __float2bfloat16(x);
  return *(ushort*)&h;
}
__device__ __forceinline__ float b2f(ushort u) {
  __hip_bfloat16 h = *(__hip_bfloat16*)&u;
  return __bfloat162float(h);
}
// fp32 -> 2-way split (hi+lo), err ~2^-17 |x|
__device__ __forceinline__ void split1(float x, ushort& h, ushort& l) {
  h = f2b(x);
  l = f2b(x - b2f(h));
}
// fp32 -> 3-way split (a+b+c), err ~2^-27 |x|  (F/M path, proven)
__device__ __forceinline__ void split3(float x, ushort& a, ushort& b, ushort& c) {
  a = f2b(x);
  float r1 = x - b2f(a);
  b = f2b(r1);
  c = f2b(r1 - b2f(b));
}

#define MFMA(d, A, B) d = __builtin_amdgcn_mfma_f32_16x16x32_bf16(A, B, d, 0, 0, 0)

// ---------------- merged prep: G, M0, M1, W1/W2 splits, zero(out) ----------------
// block ranges: [0] G | [1,129) M0 | [129,385) M1 | [385,769) splitW | [769,833) zero

__global__ __launch_bounds__(256) void prep_all_kernel(
    const float* __restrict__ Wq0, const float* __restrict__ Wk0,
    const float* __restrict__ Wq1, const float* __restrict__ Wk1,
    float* __restrict__ G,
    const float* __restrict__ Wv0, const float* __restrict__ Wo0,
    ushort* __restrict__ M0a, ushort* __restrict__ M0b, ushort* __restrict__ M0c,
    const float* __restrict__ Wv1, const float* __restrict__ Wo1,
    ushort* __restrict__ M1a, ushort* __restrict__ M1b, ushort* __restrict__ M1c,
    const float* __restrict__ W1, ushort* __restrict__ W1hi, ushort* __restrict__ W1lo,
    const float* __restrict__ W2, ushort* __restrict__ W2hi, ushort* __restrict__ W2lo,
    unsigned long long* __restrict__ out64)
{
  int blk = blockIdx.x, t = threadIdx.x;
  if (blk == 0) {
    if (t >= 32) return;
    int l = t >> 4, h = (t >> 2) & 3, a = (t >> 1) & 1, b = t & 1;
    const float* Wq = l ? Wq1 : Wq0;
    const float* Wk = l ? Wk1 : Wk0;
    float acc = 0.f;
    for (int c = 0; c < 128; c++)
      acc += Wq[(h * 128 + c) * 2 + a] * Wk[(h * 128 + c) * 2 + b];
    G[t] = acc;
  } else if (blk < 385) {
    // folded M = Wv^T-contract-Wo, triple-split
    int D, idx;
    const float *Wv, *Wo;
    ushort *Ma, *Mb, *Mc;
    if (blk < 129) { D = DIN; idx = (blk - 1) * 256 + t; Wv = Wv0; Wo = Wo0; Ma = M0a; Mb = M0b; Mc = M0c; }
    else           { D = HID; idx = (blk - 129) * 256 + t; Wv = Wv1; Wo = Wo1; Ma = M1a; Mb = M1b; Mc = M1c; }
    int K4 = 4 * D;
    int o = idx / K4, hd = idx - o * K4;
    int h = hd / D, d = hd - h * D;
    const float* wv = Wv + (size_t)(h * 128) * D + d;
    const float* wo = Wo + (size_t)o * 512 + h * 128;
    float acc = 0.f;
    for (int c = 0; c < 128; c++)
      acc += wv[(size_t)c * D] * wo[c];
    split3(acc, Ma[idx], Mb[idx], Mc[idx]);
  } else if (blk < 769) {
    int i = (blk - 385) * 256 + t;
    if (i < 256 * 128) split1(W1[i], W1hi[i], W1lo[i]);
    int j = i - 256 * 128;
    if (j >= 0 && j < 256 * 256) split1(W2[j], W2hi[j], W2lo[j]);
  } else {
    int i = (blk - 769) * 256 + t;
    if (i < N_NODES) out64[i] = 0ull;   // zero output (atomic W3 accumulation)
  }
}

// ---------------- fully fused: mask build + 2-layer GAT + 3-layer MLP ----------------
// 512 threads / block, one block per 64-node graph block (grid = 256 = 1/CU).
// GAT core is round-10's proven barrier-free schedule (split3 F/M 6-term,
// split2 A/Y exact 4-term, self-shift softmax, unroll-1 head/kf loops).
// Adjacency mask built in-LDS from this block's own 448 edge rows
// (reference builds edges in (B,A,K) C-order; self-loops via init bit), and
// the whole MLP runs in-block: h2 -> split2 LDS -> W1 -> out1 (split2,
// XOR-swizzled 64KB plane union) -> W2 -> relu -> W3 dot -> global atomicAdd.
// NOTE (R12 post-mortem): head-pairing for 2x MFMA ILP regressed 81->84us
// (bottleneck is not MFMA chain ILP); this is the round-11 structure.

#define PF 136   // F plane pitch (ushort)

template <int KD>
__device__ __forceinline__ void gat_layer(
    int wave, int lm, int lq,
    const ushort* sFa, const ushort* sFb, const ushort* sFc,
    const float* psx, const float* psy,
    const float* pdx, const float* pdy,
    const unsigned long long* m64,
    const float* __restrict__ G,
    const ushort* __restrict__ Ma, const ushort* __restrict__ Mb,
    const ushort* __restrict__ Mc,
    f32x4 hacc[4])
{
  const int K4 = 4 * KD;
  const int o = 16 * wave + lm;
#pragma unroll
  for (int i = 0; i < 4; i++) hacc[i] = (f32x4){0.f, 0.f, 0.f, 0.f};

#pragma unroll 1
  for (int h = 0; h < 4; h++) {
    f32x4 y[4];
#pragma unroll
    for (int i = 0; i < 4; i++) y[i] = (f32x4){0.f, 0.f, 0.f, 0.f};
#pragma unroll 1
    for (int kf = 0; kf < KD / 32; kf++) {
      size_t boff = (size_t)o * K4 + h * KD + kf * 32 + lq * 8;
      bf16x8 ma = *(const bf16x8*)&Ma[boff];
      bf16x8 mb = *(const bf16x8*)&Mb[boff];
      bf16x8 mc = *(const bf16x8*)&Mc[boff];
#pragma unroll
      for (int mp = 0; mp < 2; mp++) {
        int f0 = (mp * 32 + lm) * PF + kf * 32 + lq * 8;
        int f1 = (mp * 32 + 16 + lm) * PF + kf * 32 + lq * 8;
        bf16x8 fa0 = *(const bf16x8*)&sFa[f0], fa1 = *(const bf16x8*)&sFa[f1];
        bf16x8 fb0 = *(const bf16x8*)&sFb[f0], fb1 = *(const bf16x8*)&sFb[f1];
        bf16x8 fc0 = *(const bf16x8*)&sFc[f0], fc1 = *(const bf16x8*)&sFc[f1];
        f32x4 y0 = y[mp * 2], y1 = y[mp * 2 + 1];
        MFMA(y0, fa0, ma); MFMA(y1, fa1, ma);
        MFMA(y0, fa0, mb); MFMA(y1, fa1, mb);
        MFMA(y0, fb0, ma); MFMA(y1, fb1, ma);
        MFMA(y0, fa0, mc); MFMA(y1, fa1, mc);
        MFMA(y0, fc0, ma); MFMA(y1, fc1, ma);
        MFMA(y0, fb0, mb); MFMA(y1, fb1, mb);
        y[mp * 2] = y0; y[mp * 2 + 1] = y1;
      }
    }
    // redistribute y (C-layout) -> B-frags via shuffles, split2
    bf16x8 Ya[2], Yb[2];
#pragma unroll
    for (int kb = 0; kb < 2; kb++) {
#pragma unroll
      for (int j = 0; j < 8; j++) {
        int sl = ((2 * lq + (j >> 2)) & 3) * 16 + lm;
        float v0 = __shfl(y[2 * kb][j & 3], sl);
        float v1 = __shfl(y[2 * kb + 1][j & 3], sl);
        float v = (lq & 2) ? v1 : v0;
        ushort ua, ub;
        split1(v, ua, ub);
        Ya[kb][j] = (short)ua; Yb[kb][j] = (short)ub;
      }
    }
    // A@Y per dst tile
    float g0 = G[h * 4], g1 = G[h * 4 + 1], g2 = G[h * 4 + 2], g3 = G[h * 4 + 3];
#pragma unroll
    for (int mtd = 0; mtd < 4; mtd++) {
      float a0 = (g0 * pdx[mtd] + g2 * pdy[mtd]) * SCALE_F;
      float a1 = (g1 * pdx[mtd] + g3 * pdy[mtd]) * SCALE_F;
      float sshift = a0 * pdx[mtd] + a1 * pdy[mtd];
      unsigned mb0 = (unsigned)((m64[mtd] >> (8 * lq)) & 0xFF);
      unsigned mb1 = (unsigned)((m64[mtd] >> (32 + 8 * lq)) & 0xFF);
      float e[16];
      float sum = 0.f;
#pragma unroll
      for (int j = 0; j < 8; j++) {
        e[j]     = ((mb0 >> j) & 1) ? __expf(a0 * psx[j] + a1 * psy[j] - sshift) : 0.f;
        e[8 + j] = ((mb1 >> j) & 1) ? __expf(a0 * psx[8 + j] + a1 * psy[8 + j] - sshift) : 0.f;
        sum += e[j] + e[8 + j];
      }
      sum += __shfl_xor(sum, 16);
      sum += __shfl_xor(sum, 32);
      float inv = 1.f / sum;
      bf16x8 Aa[2], Ab[2];
#pragma unroll
      for (int j = 0; j < 8; j++) {
        ushort ua, ub;
        split1(e[j] * inv, ua, ub);
        Aa[0][j] = (short)ua; Ab[0][j] = (short)ub;
        split1(e[8 + j] * inv, ua, ub);
        Aa[1][j] = (short)ua; Ab[1][j] = (short)ub;
      }
#pragma unroll
      for (int kb = 0; kb < 2; kb++) {
        MFMA(hacc[mtd], Aa[kb], Ya[kb]);
        MFMA(hacc[mtd], Aa[kb], Yb[kb]);
        MFMA(hacc[mtd], Ab[kb], Ya[kb]);
        MFMA(hacc[mtd], Ab[kb], Yb[kb]);
      }
    }
  }
}

__global__ __attribute__((amdgpu_flat_work_group_size(512, 512), amdgpu_waves_per_eu(2)))
void fused_gat_kernel(
    const float* __restrict__ x, const float* __restrict__ pos,
    const int* __restrict__ srcp, const int* __restrict__ dstp,
    const float* __restrict__ G,
    const ushort* __restrict__ M0a, const ushort* __restrict__ M0b, const ushort* __restrict__ M0c,
    const ushort* __restrict__ M1a, const ushort* __restrict__ M1b, const ushort* __restrict__ M1c,
    const float* __restrict__ bo0, const float* __restrict__ bo1,
    const ushort* __restrict__ W1hi, const ushort* __restrict__ W1lo, const float* __restrict__ b1,
    const ushort* __restrict__ W2hi, const ushort* __restrict__ W2lo, const float* __restrict__ b2,
    const float* __restrict__ W3, const float* __restrict__ b3,
    float* __restrict__ outp)
{
  // 64KB union. GAT: sF planes [0,26112) + px/py [26112,26368) + smask [26368,26624).
  // MLP: h2 split2 in sFa/sFb [0,17408) (dies at B7), then out1 planes [0,32768).
  __shared__ __align__(16) ushort uBig[32768];
  ushort* sFa = uBig;
  ushort* sFb = uBig + 8704;
  ushort* sFc = uBig + 17408;
  float* pxs = (float*)(uBig + 26112);
  float* pys = (float*)(uBig + 26240);
  unsigned long long* smask = (unsigned long long*)(uBig + 26368);
  ushort* pA = uBig;
  ushort* pB = uBig + 16384;

  int b = blockIdx.x, t = threadIdx.x;
  int wave = t >> 6, lane = t & 63, lm = lane & 15, lq = lane >> 4;

  if (t < 64) {
    pxs[t] = pos[(b * 64 + t) * 2];
    pys[t] = pos[(b * 64 + t) * 2 + 1];
    smask[t] = 1ull << t;   // self-loop bit
  }
  // stage X (64x64 fp32) -> triple-split planes
  {
    const float4* gx = (const float4*)(x + (size_t)b * 64 * DIN);
#pragma unroll
    for (int i = 0; i < 2; i++) {
      int idx = t + i * 512;
      float4 v = gx[idx];
      int r = idx >> 4, c = (idx & 15) * 4;
      ushort4 ua, ub, uc;
      split3(v.x, ua.x, ub.x, uc.x); split3(v.y, ua.y, ub.y, uc.y);
      split3(v.z, ua.z, ub.z, uc.z); split3(v.w, ua.w, ub.w, uc.w);
      *(ushort4*)&sFa[r * PF + c] = ua;
      *(ushort4*)&sFb[r * PF + c] = ub;
      *(ushort4*)&sFc[r * PF + c] = uc;
    }
  }
  __syncthreads();   // B1: smask init + X visible
  // adjacency from this block's own 448 kNN edge rows (reference (B,A,K) C-order)
  if (t < 448) {
    int s = srcp[b * 448 + t];
    int d = dstp[b * 448 + t];
    atomicOr(&smask[d & 63], 1ull << (s & 63));
  }
  __syncthreads();   // B2
  unsigned long long m64[4];
#pragma unroll
  for (int mtd = 0; mtd < 4; mtd++) m64[mtd] = smask[mtd * 16 + lm];

  float psx[16], psy[16], pdx[4], pdy[4];
#pragma unroll
  for (int j = 0; j < 8; j++) {
    psx[j] = pxs[8 * lq + j];          psy[j] = pys[8 * lq + j];
    psx[8 + j] = pxs[32 + 8 * lq + j]; psy[8 + j] = pys[32 + 8 * lq + j];
  }
#pragma unroll
  for (int mtd = 0; mtd < 4; mtd++) {
    pdx[mtd] = pxs[mtd * 16 + lm];
    pdy[mtd] = pys[mtd * 16 + lm];
  }

  f32x4 hacc[4];
  gat_layer<DIN>(wave, lm, lq, sFa, sFb, sFc, psx, psy, pdx, pdy, m64,
                 G, M0a, M0b, M0c, hacc);
  __syncthreads();   // B3: layer-0 F reads done
  int o = 16 * wave + lm;
  {
    float bv = bo0[o];
#pragma unroll
    for (int mtd = 0; mtd < 4; mtd++)
#pragma unroll
      for (int r = 0; r < 4; r++) {
        int dst = mtd * 16 + lq * 4 + r;
        ushort ua, ub, uc;
        split3(tanhf(hacc[mtd][r] + bv), ua, ub, uc);
        sFa[dst * PF + o] = ua;
        sFb[dst * PF + o] = ub;
        sFc[dst * PF + o] = uc;
      }
  }
  __syncthreads();   // B4
  gat_layer<HID>(wave, lm, lq, sFa, sFb, sFc, psx, psy, pdx, pdy, m64,
                 G + 16, M1a, M1b, M1c, hacc);
  // h2 in regs
  float h2v[4][4];
  {
    float bv = bo1[o];
#pragma unroll
    for (int mtd = 0; mtd < 4; mtd++)
#pragma unroll
      for (int r = 0; r < 4; r++)
        h2v[mtd][r] = tanhf(hacc[mtd][r] + bv);
  }
  __syncthreads();   // B5: layer-1 sF reads done
  // store h2 split2 into sFa/sFb
#pragma unroll
  for (int mtd = 0; mtd < 4; mtd++)
#pragma unroll
    for (int r = 0; r < 4; r++) {
      int dst = mtd * 16 + lq * 4 + r;
      ushort hh, ll;
      split1(h2v[mtd][r], hh, ll);
      sFa[dst * PF + o] = hh;
      sFb[dst * PF + o] = ll;
    }
  __syncthreads();   // B6
  // ---- W1: out1 = relu(h2 @ W1^T + b1); wave cols [32w, 32w+32) ----
  f32x4 y1[2][4];
#pragma unroll
  for (int ti = 0; ti < 2; ti++)
#pragma unroll
    for (int mtd = 0; mtd < 4; mtd++) y1[ti][mtd] = (f32x4){0.f, 0.f, 0.f, 0.f};
#pragma unroll 1
  for (int kf = 0; kf < 4; kf++) {
    int ko = kf * 32 + lq * 8;
    bf16x8 bh0 = *(const bf16x8*)&W1hi[(size_t)(32 * wave + lm) * 128 + ko];
    bf16x8 bl0 = *(const bf16x8*)&W1lo[(size_t)(32 * wave + lm) * 128 + ko];
    bf16x8 bh1 = *(const bf16x8*)&W1hi[(size_t)(32 * wave + 16 + lm) * 128 + ko];
    bf16x8 bl1 = *(const bf16x8*)&W1lo[(size_t)(32 * wave + 16 + lm) * 128 + ko];
#pragma unroll
    for (int mtd = 0; mtd < 4; mtd++) {
      bf16x8 ah = *(const bf16x8*)&sFa[(mtd * 16 + lm) * PF + ko];
      bf16x8 al = *(const bf16x8*)&sFb[(mtd * 16 + lm) * PF + ko];
      MFMA(y1[0][mtd], ah, bh0);
      MFMA(y1[0][mtd], ah, bl0);
      MFMA(y1[0][mtd], al, bh0);
      MFMA(y1[1][mtd], ah, bh1);
      MFMA(y1[1][mtd], ah, bl1);
      MFMA(y1[1][mtd], al, bh1);
    }
  }
  __syncthreads();   // B7: all W1 h2-reads done; pA/pB may overwrite
  // store out1 split2, XOR-swizzled: elem (row,k) at row*256 + (k ^ ((row&15)<<3))
#pragma unroll
  for (int ti = 0; ti < 2; ti++) {
    int col = 32 * wave + ti * 16 + lm;
    float bv = b1[col];
#pragma unroll
    for (int mtd = 0; mtd < 4; mtd++)
#pragma unroll
      for (int r = 0; r < 4; r++) {
        int row = mtd * 16 + lq * 4 + r;
        float v = fmaxf(y1[ti][mtd][r] + bv, 0.f);
        ushort hh, ll;
        split1(v, hh, ll);
        int cc = col ^ ((row & 15) << 3);
        pA[row * 256 + cc] = hh;
        pB[row * 256 + cc] = ll;
      }
  }
  __syncthreads();   // B8
  // ---- W2 + fused W3 ----
  f32x4 y2[2][4];
#pragma unroll
  for (int ti = 0; ti < 2; ti++)
#pragma unroll
    for (int mtd = 0; mtd < 4; mtd++) y2[ti][mtd] = (f32x4){0.f, 0.f, 0.f, 0.f};
#pragma unroll 1
  for (int kf = 0; kf < 8; kf++) {
    int ko = kf * 32 + lq * 8;
    bf16x8 bh0 = *(const bf16x8*)&W2hi[(size_t)(32 * wave + lm) * 256 + ko];
    bf16x8 bl0 = *(const bf16x8*)&W2lo[(size_t)(32 * wave + lm) * 256 + ko];
    bf16x8 bh1 = *(const bf16x8*)&W2hi[(size_t)(32 * wave + 16 + lm) * 256 + ko];
    bf16x8 bl1 = *(const bf16x8*)&W2lo[(size_t)(32 * wave + 16 + lm) * 256 + ko];
#pragma unroll
    for (int mtd = 0; mtd < 4; mtd++) {
      int row = mtd * 16 + lm;
      int cc = ko ^ ((row & 15) << 3);
      bf16x8 ah = *(const bf16x8*)&pA[row * 256 + cc];
      bf16x8 al = *(const bf16x8*)&pB[row * 256 + cc];
      MFMA(y2[0][mtd], ah, bh0);
      MFMA(y2[0][mtd], ah, bl0);
      MFMA(y2[0][mtd], al, bh0);
      MFMA(y2[1][mtd], ah, bh1);
      MFMA(y2[1][mtd], ah, bl1);
      MFMA(y2[1][mtd], al, bh1);
    }
  }
  // W3 epilogue: per-row dot over this wave's 32 cols, lm-reduce, atomicAdd
  {
    int c0 = 32 * wave + lm, c1 = c0 + 16;
    float w300 = W3[c0], w301 = W3[c1];
    float w310 = W3[256 + c0], w311 = W3[256 + c1];
    float b20 = b2[c0], b21 = b2[c1];
    float bb0 = (wave == 0) ? b3[0] : 0.f;
    float bb1 = (wave == 0) ? b3[1] : 0.f;
#pragma unroll
    for (int mtd = 0; mtd < 4; mtd++)
#pragma unroll
      for (int r = 0; r < 4; r++) {
        float va = fmaxf(y2[0][mtd][r] + b20, 0.f);
        float vb = fmaxf(y2[1][mtd][r] + b21, 0.f);
        float s0 = va * w300 + vb * w301;
        float s1 = va * w310 + vb * w311;
        s0 += __shfl_xor(s0, 1); s0 += __shfl_xor(s0, 2);
        s0 += __shfl_xor(s0, 4); s0 += __shfl_xor(s0, 8);
        s1 += __shfl_xor(s1, 1); s1 += __shfl_xor(s1, 2);
        s1 += __shfl_xor(s1, 4); s1 += __shfl_xor(s1, 8);
        if (lm == 0) {
          int row = b * 64 + mtd * 16 + lq * 4 + r;
          atomicAdd(&outp[row * 2 + 0], s0 + bb0);
          atomicAdd(&outp[row * 2 + 1], s1 + bb1);
        }
      }
  }
}

// ---------------- launch ----------------

extern "C" void kernel_launch(void* const* d_in, const int* in_sizes, int n_in,
                              void* d_out, int out_size, void* d_ws, size_t ws_size,
                              hipStream_t stream) {
  const float* x     = (const float*)d_in[0];
  const float* pos   = (const float*)d_in[1];
  const int*   ei    = (const int*)d_in[2];
  const float* l0_Wq = (const float*)d_in[3];
  const float* l0_Wk = (const float*)d_in[4];
  const float* l0_Wv = (const float*)d_in[5];
  const float* l0_Wo = (const float*)d_in[6];
  const float* l0_bo = (const float*)d_in[7];
  const float* l1_Wq = (const float*)d_in[8];
  const float* l1_Wk = (const float*)d_in[9];
  const float* l1_Wv = (const float*)d_in[10];
  const float* l1_Wo = (const float*)d_in[11];
  const float* l1_bo = (const float*)d_in[12];
  const float* W1    = (const float*)d_in[13];
  const float* b1    = (const float*)d_in[14];
  const float* W2    = (const float*)d_in[15];
  const float* b2    = (const float*)d_in[16];
  const float* W3    = (const float*)d_in[17];
  const float* b3    = (const float*)d_in[18];
  float* outp = (float*)d_out;

  int E = in_sizes[2] / 2;
  const int* srcp = ei;
  const int* dstp = ei + E;

  char* base = (char*)d_ws;
  size_t off = 0;
  auto alloc = [&](size_t bytes) -> void* {
    void* p = base + off;
    off = (off + bytes + 255) & ~(size_t)255;
    return p;
  };
  float*  G   = (float*)alloc(32 * sizeof(float));
  ushort* M0a = (ushort*)alloc((size_t)128 * 256 * 2);
  ushort* M0b = (ushort*)alloc((size_t)128 * 256 * 2);
  ushort* M0c = (ushort*)alloc((size_t)128 * 256 * 2);
  ushort* M1a = (ushort*)alloc((size_t)128 * 512 * 2);
  ushort* M1b = (ushort*)alloc((size_t)128 * 512 * 2);
  ushort* M1c = (ushort*)alloc((size_t)128 * 512 * 2);
  ushort* W1hi = (ushort*)alloc((size_t)256 * 128 * 2);
  ushort* W1lo = (ushort*)alloc((size_t)256 * 128 * 2);
  ushort* W2hi = (ushort*)alloc((size_t)256 * 256 * 2);
  ushort* W2lo = (ushort*)alloc((size_t)256 * 256 * 2);

  // prep: G, M folds, W splits, zero(out)
  prep_all_kernel<<<833, 256, 0, stream>>>(
      l0_Wq, l0_Wk, l1_Wq, l1_Wk, G,
      l0_Wv, l0_Wo, M0a, M0b, M0c,
      l1_Wv, l1_Wo, M1a, M1b, M1c,
      W1, W1hi, W1lo, W2, W2hi, W2lo,
      (unsigned long long*)outp);

  // fully fused network
  fused_gat_kernel<<<N_NODES / 64, 512, 0, stream>>>(
      x, pos, srcp, dstp, G, M0a, M0b, M0c, M1a, M1b, M1c, l0_bo, l1_bo,
      W1hi, W1lo, b1, W2hi, W2lo, b2, W3, b3, outp);

  (void)n_in; (void)out_size; (void)ws_size;
}